// Round 1
// 634.876 us; speedup vs baseline: 1.1844x; 1.1844x over previous
//
#include <hip/hip_runtime.h>
#include <hip/hip_bf16.h>

// RWKV7 WKV chunked scan. T=4096, H=32, N=64. Output fp32 (y then S_final).
//
// Pass 1 (R5): TWO waves per (chunk, head). The fused P/M scan is column-split:
//   wave wv owns state columns [wv*32, wv*32+32) of BOTH SP and SM (64 VGPRs).
//   Per step each wave computes partial sa = S_row.a over its columns; the two
//   partials are exchanged through double-buffered LDS with ONE __syncthreads
//   per step; same for the y/q output dots (deferred one step so their
//   exchange shares the same barrier). Broadcast vectors are loaded at element
//   j0+(lane&31) so every readlane uses an inline-constant lane index 0..31.
//   This halves per-wave instructions and doubles occupancy (2 -> 4 waves/SIMD)
//   vs R4, which was latency-bound at VALUBusy 53% / Occupancy 14.7%.
//   (R1: per-element LDS broadcast = LDS-issue bound, 392us. R2: s_load
//   broadcast = scalar-cache latency chain, regression. This uses 4 LDS
//   accesses/step, a different regime.)
// Pass 2: sequential chain over 64 chunks: S_c = S_{c-1} M_c + P_c.
// Pass 3: y_t = y_local_t + S_before[c] @ rho_t.

#define Tt 4096
#define Hh 32
#define Nn 64
#define Ll 64              // chunk length
#define Cc 64              // number of chunks
#define HN (Hh * Nn)       // 2048
#define NN (Nn * Nn)       // 4096

__device__ __forceinline__ float ldf(const float* p) { return *p; }
__device__ __forceinline__ float ldf(const __hip_bfloat16* p) { return __bfloat162float(*p); }
__device__ __forceinline__ void stf(float* p, float v) { *p = v; }
__device__ __forceinline__ void stf(__hip_bfloat16* p, float v) { *p = __float2bfloat16(v); }

__device__ __forceinline__ float rl(float v, int j) {
    return __int_as_float(__builtin_amdgcn_readlane(__float_as_int(v), j));
}

// ---------------------------------------------------------------- pass 1
template <typename ST>
__global__ __launch_bounds__(128, 4)
void pass1_scan(const float* __restrict__ rr, const float* __restrict__ ww,
                const float* __restrict__ kk, const float* __restrict__ vv,
                const float* __restrict__ aa, const float* __restrict__ bb,
                float* __restrict__ ylocal,
                ST* __restrict__ rho, ST* __restrict__ Mt, ST* __restrict__ Pt)
{
    const int c    = blockIdx.x >> 5;      // chunk
    const int h    = blockIdx.x & 31;      // head
    const int tid  = threadIdx.x;
    const int lane = tid & 63;             // row i
    const int wv   = tid >> 6;             // column-half 0/1
    const int j0   = __builtin_amdgcn_readfirstlane(wv << 5);

    // partial-exchange buffers, double-buffered over step parity
    __shared__ float2 ex1[2][2][64];       // [par][wave][row] = {saP, saM} partials
    __shared__ float  ex2[2][2][64];       // [par][wave][row] = partial the OTHER wave finalizes

    float SP[32];                          // P scan, local columns
    float SM[32];                          // M scan, local columns
    #pragma unroll
    for (int jj = 0; jj < 32; ++jj) {
        SP[jj] = 0.0f;
        SM[jj] = (j0 + jj == lane) ? 1.0f : 0.0f;
    }

    int base = (c * Ll * Hh + h) * Nn;     // element offset of step t
    const int lv = j0 + (lane & 31);       // broadcast-source element this lane carries
    // broadcast vectors: lane l holds element j0+(l&31)  (readlane index = const 0..31)
    float ca = aa[base + lv];
    float cw = ww[base + lv];
    float cb = bb[base + lv];
    float cr = rr[base + lv];
    float ck = kk[base + lv];
    float cv = vv[base + lane];            // per-row value (full vector per lane)

    float py = 0.f, pq = 0.f;              // y/q partials of step t-1 (exchanged next iter)

    for (int t = 0; t < Ll; ++t) {
        // partial sa over local columns (shared a broadcasts between both scans)
        float p0 = 0.f, p1 = 0.f, m0 = 0.f, m1 = 0.f;
        #pragma unroll
        for (int jj = 0; jj < 32; jj += 2) {
            const float a0 = rl(ca, jj), a1 = rl(ca, jj + 1);
            p0 += SP[jj + 0] * a0;  m0 += SM[jj + 0] * a0;
            p1 += SP[jj + 1] * a1;  m1 += SM[jj + 1] * a1;
        }
        const float pP = p0 + p1, pM = m0 + m1;

        ex1[t & 1][wv][lane] = make_float2(pP, pM);
        if (t > 0) ex2[(t - 1) & 1][wv][lane] = (wv == 0) ? pq : py;
        __syncthreads();
        const float2 o = ex1[t & 1][wv ^ 1][lane];
        const float saP = pP + o.x;
        const float saM = pM + o.y;
        if (t > 0) {                        // finish + store step t-1 outputs
            const int ob = base - HN + lane;
            if (wv == 0) ylocal[ob] = py + ex2[(t - 1) & 1][1][lane];
            else         stf(&rho[ob], pq + ex2[(t - 1) & 1][0][lane]);
        }

        // prefetch next step's vectors (uniform branch; hides under update loop)
        float na = 0.f, nw = 0.f, nb = 0.f, nr = 0.f, nk = 0.f, nv = 0.f;
        if (t + 1 < Ll) {
            const int b2 = base + HN;
            na = aa[b2 + lv]; nw = ww[b2 + lv]; nb = bb[b2 + lv];
            nr = rr[b2 + lv]; nk = kk[b2 + lv]; nv = vv[b2 + lane];
        }

        // S = S*w + sa*b (+ v*k); accumulate local y/q partials
        float y0 = 0.f, y1 = 0.f, q0 = 0.f, q1 = 0.f;
        #pragma unroll
        for (int jj = 0; jj < 32; jj += 2) {
            const float w0 = rl(cw, jj), w1 = rl(cw, jj + 1);
            const float b0 = rl(cb, jj), b1 = rl(cb, jj + 1);
            const float k0 = rl(ck, jj), k1 = rl(ck, jj + 1);
            const float r0 = rl(cr, jj), r1 = rl(cr, jj + 1);
            SP[jj + 0] = SP[jj + 0] * w0 + saP * b0 + cv * k0;
            SP[jj + 1] = SP[jj + 1] * w1 + saP * b1 + cv * k1;
            SM[jj + 0] = SM[jj + 0] * w0 + saM * b0;
            SM[jj + 1] = SM[jj + 1] * w1 + saM * b1;
            y0 += SP[jj + 0] * r0;
            y1 += SP[jj + 1] * r1;
            q0 += SM[jj + 0] * r0;
            q1 += SM[jj + 1] * r1;
        }
        py = y0 + y1;
        pq = q0 + q1;

        base += HN;
        ca = na; cw = nw; cb = nb; cr = nr; ck = nk; cv = nv;
    }

    // drain the deferred outputs of the final step
    {
        ex2[(Ll - 1) & 1][wv][lane] = (wv == 0) ? pq : py;
        __syncthreads();
        const int ob = base - HN + lane;
        if (wv == 0) ylocal[ob] = py + ex2[(Ll - 1) & 1][1][lane];
        else         stf(&rho[ob], pq + ex2[(Ll - 1) & 1][0][lane]);
    }

    // chunk-final matrices, stored transposed: [c][h][col j][row lane]
    const size_t mb = ((size_t)(c * Hh) + h) * NN;
    #pragma unroll
    for (int jj = 0; jj < 32; ++jj) {
        stf(&Pt[mb + (size_t)(j0 + jj) * Nn + lane], SP[jj]);
        stf(&Mt[mb + (size_t)(j0 + jj) * Nn + lane], SM[jj]);
    }
}

// ---------------------------------------------------------------- pass 2
template <typename ST>
__global__ __launch_bounds__(256, 1)
void pass2_chain(const ST* __restrict__ Mt, const ST* __restrict__ Pt,
                 const float* __restrict__ st0, ST* __restrict__ Sst,
                 float* __restrict__ sfin)
{
    const int h   = blockIdx.x >> 3;
    const int g   = blockIdx.x & 7;
    const int tid = threadIdx.x;
    const int li  = tid >> 5;          // 0..7 local row
    const int i   = g * 8 + li;        // global row
    const int j2  = (tid & 31) * 2;    // column pair

    __shared__ float Mlds[Nn][Nn + 4]; // [row k][col j]
    __shared__ float Slds[8][Nn + 1];  // [li][col]

    float s0 = st0[(h * Nn + i) * Nn + j2];
    float s1 = st0[(h * Nn + i) * Nn + j2 + 1];
    Slds[li][j2]     = s0;
    Slds[li][j2 + 1] = s1;

    // prefetch chunk 0: Mt flat index lin = col*64 + row; Pt[col*64 + row]
    float mpre[16];
    {
        const size_t mb = (size_t)h * NN;
        #pragma unroll
        for (int q = 0; q < 16; ++q) mpre[q] = ldf(&Mt[mb + (size_t)tid * 16 + q]);
    }
    float pp0 = ldf(&Pt[(size_t)h * NN + (size_t)j2 * Nn + i]);
    float pp1 = ldf(&Pt[(size_t)h * NN + (size_t)(j2 + 1) * Nn + i]);
    __syncthreads();

    for (int c = 0; c < Cc; ++c) {
        // S_before[c] out (row-major [i][j])
        const size_t sb = ((size_t)(c * Hh) + h) * NN;
        stf(&Sst[sb + (size_t)i * Nn + j2],     s0);
        stf(&Sst[sb + (size_t)i * Nn + j2 + 1], s1);

        // un-transpose prefetched Mt into Mlds[row][col]
        #pragma unroll
        for (int q = 0; q < 16; ++q) {
            const int lin = tid * 16 + q;          // lin = col*64 + row
            Mlds[lin & 63][lin >> 6] = mpre[q];
        }
        __syncthreads();

        float np0 = 0.f, np1 = 0.f;
        if (c + 1 < Cc) {                          // prefetch next chunk during k-loop
            const size_t mb2 = ((size_t)((c + 1) * Hh) + h) * NN;
            #pragma unroll
            for (int q = 0; q < 16; ++q) mpre[q] = ldf(&Mt[mb2 + (size_t)tid * 16 + q]);
            np0 = ldf(&Pt[mb2 + (size_t)j2 * Nn + i]);
            np1 = ldf(&Pt[mb2 + (size_t)(j2 + 1) * Nn + i]);
        }

        // newS[i][j] = sum_k S[i][k] * M[k][j] + P[i][j]
        float a0 = pp0, b0 = 0.f, a1 = pp1, b1 = 0.f;
        #pragma unroll
        for (int kq = 0; kq < Nn; kq += 2) {
            const float se = Slds[li][kq];
            const float so = Slds[li][kq + 1];
            a0 += se * Mlds[kq][j2];
            b0 += so * Mlds[kq + 1][j2];
            a1 += se * Mlds[kq][j2 + 1];
            b1 += so * Mlds[kq + 1][j2 + 1];
        }
        const float acc0 = a0 + b0, acc1 = a1 + b1;
        __syncthreads();
        Slds[li][j2]     = acc0;
        Slds[li][j2 + 1] = acc1;
        s0 = acc0; s1 = acc1;
        pp0 = np0; pp1 = np1;
        __syncthreads();
    }

    // final state -> d_out tail (fp32)
    sfin[(h * Nn + i) * Nn + j2]     = s0;
    sfin[(h * Nn + i) * Nn + j2 + 1] = s1;
}

// ---------------------------------------------------------------- pass 3
template <typename ST>
__global__ __launch_bounds__(256, 4)
void pass3_fix(const ST* __restrict__ rho, const ST* __restrict__ Sst,
               float* __restrict__ y)
{
    const int c    = blockIdx.x / Hh;
    const int h    = blockIdx.x % Hh;
    const int tid  = threadIdx.x;
    const int lane = tid & 63;   // output row i
    const int tq   = tid >> 6;   // 0..3

    __shared__ float Rlds[Ll][Nn];   // rho rows for this chunk

    {
        const int tl = tid >> 2;
        const int j0 = (tid & 3) * 16;
        const int gb = ((c * Ll + tl) * Hh + h) * Nn + j0;
        #pragma unroll
        for (int q = 0; q < 16; ++q) Rlds[tl][j0 + q] = ldf(&rho[gb + q]);
    }

    float Srow[Nn];  // S_before[c][h] row `lane`
    {
        const size_t sb = ((size_t)(c * Hh) + h) * NN + (size_t)lane * Nn;
        #pragma unroll
        for (int j = 0; j < Nn; ++j) Srow[j] = ldf(&Sst[sb + j]);
    }
    __syncthreads();

    for (int m = 0; m < 16; ++m) {
        const int tl = tq + m * 4;
        float a0 = 0.f, a1 = 0.f, a2 = 0.f, a3 = 0.f;
        #pragma unroll
        for (int j = 0; j < Nn; j += 4) {
            a0 += Srow[j + 0] * Rlds[tl][j + 0];
            a1 += Srow[j + 1] * Rlds[tl][j + 1];
            a2 += Srow[j + 2] * Rlds[tl][j + 2];
            a3 += Srow[j + 3] * Rlds[tl][j + 3];
        }
        const int oy = ((c * Ll + tl) * Hh + h) * Nn + lane;
        y[oy] = y[oy] + ((a0 + a1) + (a2 + a3));
    }
}

// ------------------------------------------- zero-scratch sequential fallback
__global__ __launch_bounds__(64, 1)
void seq_scan(const float* __restrict__ rr, const float* __restrict__ ww,
              const float* __restrict__ kk, const float* __restrict__ vv,
              const float* __restrict__ aa, const float* __restrict__ bb,
              const float* __restrict__ st0,
              float* __restrict__ y, float* __restrict__ sfin)
{
    const int h    = blockIdx.x;
    const int lane = threadIdx.x;          // row i

    float S[Nn];
    #pragma unroll
    for (int j = 0; j < Nn; ++j) S[j] = st0[(h * Nn + lane) * Nn + j];

    int base = h * Nn;
    float ca = aa[base + lane], cw = ww[base + lane], cb = bb[base + lane];
    float cr = rr[base + lane], ck = kk[base + lane], cv = vv[base + lane];

    for (int t = 0; t < Tt; ++t) {
        float na = 0.f, nw = 0.f, nb = 0.f, nr = 0.f, nk = 0.f, nv = 0.f;
        if (t + 1 < Tt) {
            const int b2 = base + HN + lane;
            na = aa[b2]; nw = ww[b2]; nb = bb[b2];
            nr = rr[b2]; nk = kk[b2]; nv = vv[b2];
        }

        float s0 = 0.f, s1 = 0.f;
        #pragma unroll
        for (int j = 0; j < Nn; j += 2) {
            s0 += S[j + 0] * rl(ca, j);
            s1 += S[j + 1] * rl(ca, j + 1);
        }
        const float sa = s0 + s1;

        float y0 = 0.f, y1 = 0.f;
        #pragma unroll
        for (int j = 0; j < Nn; j += 2) {
            const float w0 = rl(cw, j), w1 = rl(cw, j + 1);
            const float b0 = rl(cb, j), b1 = rl(cb, j + 1);
            const float k0 = rl(ck, j), k1 = rl(ck, j + 1);
            const float r0 = rl(cr, j), r1 = rl(cr, j + 1);
            S[j + 0] = S[j + 0] * w0 + sa * b0 + cv * k0;
            S[j + 1] = S[j + 1] * w1 + sa * b1 + cv * k1;
            y0 += S[j + 0] * r0;
            y1 += S[j + 1] * r1;
        }
        y[base + lane] = y0 + y1;
        base += HN;
        ca = na; cw = nw; cb = nb; cr = nr; ck = nk; cv = nv;
    }

    #pragma unroll
    for (int j = 0; j < Nn; ++j) sfin[(h * Nn + lane) * Nn + j] = S[j];
}

// ---------------------------------------------------------------- launch
extern "C" void kernel_launch(void* const* d_in, const int* in_sizes, int n_in,
                              void* d_out, int out_size, void* d_ws, size_t ws_size,
                              hipStream_t stream)
{
    const float* r  = (const float*)d_in[0];
    const float* w  = (const float*)d_in[1];
    const float* k  = (const float*)d_in[2];
    const float* v  = (const float*)d_in[3];
    const float* a  = (const float*)d_in[4];
    const float* b  = (const float*)d_in[5];
    const float* st = (const float*)d_in[6];

    float* out  = (float*)d_out;
    float* yl   = out;                       // y region (also y_local scratch)
    float* sfin = out + (size_t)Tt * HN;     // S_final region

    const size_t nTHN = (size_t)Tt * HN;       // 8388608 (rho)
    const size_t nCH  = (size_t)Cc * Hh * NN;  // 8388608 (each of Mt, Pt, Sst)
    const size_t need = nTHN + 3 * nCH;        // scratch element count

    if (ws_size >= need * sizeof(float)) {
        float* ws  = (float*)d_ws;
        float* rho = ws;
        float* Mt  = ws + nTHN;
        float* Pt  = Mt + nCH;
        float* Ss  = Pt + nCH;
        hipLaunchKernelGGL((pass1_scan<float>), dim3(Cc * Hh), dim3(128), 0, stream,
                           r, w, k, v, a, b, yl, rho, Mt, Pt);
        hipLaunchKernelGGL((pass2_chain<float>), dim3(Hh * 8), dim3(256), 0, stream,
                           Mt, Pt, st, Ss, sfin);
        hipLaunchKernelGGL((pass3_fix<float>), dim3(Cc * Hh), dim3(256), 0, stream,
                           rho, Ss, out);
    } else if (ws_size >= need * sizeof(__hip_bfloat16)) {
        __hip_bfloat16* ws  = (__hip_bfloat16*)d_ws;
        __hip_bfloat16* rho = ws;
        __hip_bfloat16* Mt  = ws + nTHN;
        __hip_bfloat16* Pt  = Mt + nCH;
        __hip_bfloat16* Ss  = Pt + nCH;
        hipLaunchKernelGGL((pass1_scan<__hip_bfloat16>), dim3(Cc * Hh), dim3(128), 0, stream,
                           r, w, k, v, a, b, yl, rho, Mt, Pt);
        hipLaunchKernelGGL((pass2_chain<__hip_bfloat16>), dim3(Hh * 8), dim3(256), 0, stream,
                           Mt, Pt, st, Ss, sfin);
        hipLaunchKernelGGL((pass3_fix<__hip_bfloat16>), dim3(Cc * Hh), dim3(256), 0, stream,
                           rho, Ss, out);
    } else {
        // no usable scratch: correct-but-slow sequential scan
        hipLaunchKernelGGL(seq_scan, dim3(Hh), dim3(64), 0, stream,
                           r, w, k, v, a, b, st, yl, sfin);
    }
}